// Round 11
// baseline (227.369 us; speedup 1.0000x reference)
//
#include <hip/hip_runtime.h>
#include <stdint.h>

// ---------------------------------------------------------------------------
// MLP_42872363549033: ViT-B quantized MLP, exact-i8 formulation.
//   h   = gelu( quant(x,ka1) @ quant(W1,kw1)^T + b1 )
//   out = quant(h,ka2) @ quant(W2,kw2)^T + b2
// quant(x,K) = int8 * (K/127) exactly -> i8 MFMA with i32 accumulation.
//
// Round 10 kernel (2nd submission; round-10 bench hit GPU acquisition
// timeout): round-9 geometry unchanged (128x128 tile, BK=64B, static dbuf,
// 2-way-free swizzle, XCD block swizzle, fused quant). ONE change: counted
// vmcnt schedule — raw s_barrier (no implicit vmcnt(0) drain) + explicit
// s_waitcnt vmcnt(4); prefetch loads stay in flight across barriers (T4).
// ---------------------------------------------------------------------------

typedef __attribute__((ext_vector_type(4))) int i32x4;

static constexpr int MROWS = 12608;   // 64 * 197
static constexpr int MPAD  = 12672;   // 99 * 128
static constexpr int DDIM  = 768;
static constexpr int HDIM  = 3072;

__device__ __forceinline__ int quant_one(float x, float K) {
    float xc = x / K;
    xc = fminf(fmaxf(xc, -1.0f), 1.0f);
    return (int)rintf(xc * 127.0f);   // v_rndne round-half-even = jnp.round
}

// ---- fused quantize: hidden | W1 | W2 in one launch -----------------------
__global__ void quant_fused_kernel(const float* __restrict__ x,
                                   const float* __restrict__ w1,
                                   const float* __restrict__ w2,
                                   int8_t* __restrict__ a8,
                                   int8_t* __restrict__ w1q,
                                   int8_t* __restrict__ w2q,
                                   const float* __restrict__ ka1,
                                   const float* __restrict__ kw1,
                                   const float* __restrict__ kw2) {
    constexpr int G1 = MPAD * DDIM / 4;     // a8 groups (incl. pad rows)
    constexpr int GV = MROWS * DDIM / 4;    // valid a8 groups
    constexpr int G2 = HDIM * DDIM / 4;     // w1q / w2q groups
    int i = blockIdx.x * 256 + threadIdx.x;
    const float4* src; int* dst; float K; int idx; bool valid = true;
    if (i < G1) {
        idx = i;           src = (const float4*)x;  dst = (int*)a8;  K = ka1[0];
        valid = i < GV;                      // pad rows -> 0
    } else if (i < G1 + G2) {
        idx = i - G1;      src = (const float4*)w1; dst = (int*)w1q; K = kw1[0];
    } else if (i < G1 + 2 * G2) {
        idx = i - G1 - G2; src = (const float4*)w2; dst = (int*)w2q; K = kw2[0];
    } else return;
    int packed = 0;
    if (valid) {
        float4 v = src[idx];
        packed = (quant_one(v.x, K) & 255)
               | ((quant_one(v.y, K) & 255) << 8)
               | ((quant_one(v.z, K) & 255) << 16)
               | ((quant_one(v.w, K) & 255) << 24);
    }
    dst[idx] = packed;
}

// ---- async global -> LDS, 16B per lane ------------------------------------
__device__ __forceinline__ void load16_to_lds(const int8_t* g, const int8_t* l) {
    __builtin_amdgcn_global_load_lds(
        (const __attribute__((address_space(1))) void*)g,
        (__attribute__((address_space(3))) void*)l, 16, 0, 0);
}

// raw barrier / counted waits: memory clobber = compiler-level fence so
// ds_read/gld_lds cannot be hoisted/sunk across (no implicit vmcnt(0) drain).
#define BAR()    asm volatile("s_barrier" ::: "memory")
#define VMCNT4() asm volatile("s_waitcnt vmcnt(4)" ::: "memory")
#define VMCNT0() asm volatile("s_waitcnt vmcnt(0)" ::: "memory")

// ---- i8 GEMM: 128x128 tile, BK=64B, 4 waves (2x2), mfma_i32_16x16x64_i8 ---
// A: [MPAD][KD] K-major, B: [ND][KD] K-major. C[m,n] = sum_k A[m,k]*B[n,k].
// LDS tile [128 rows][4 slots of 16B]; slot s holds global chunk s^((row>>1)&3).
// Schedule: 2-tile-deep counted-vmcnt pipeline; 8 loads in flight steady-state,
// vmcnt(4) before each compute (own oldest-4 = current tile landed), barrier,
// compute, barrier, restage (never drains to 0 in main loop).
template<int KD, int ND, bool EPI1>
__global__ __launch_bounds__(256, 3)
void gemm_i8_kernel(const int8_t* __restrict__ A, const int8_t* __restrict__ B,
                    int8_t* __restrict__ qout, float* __restrict__ fout,
                    const float* __restrict__ bias,
                    const float* __restrict__ kA, const float* __restrict__ kW,
                    const float* __restrict__ kQ) {
    __shared__ __align__(16) int8_t As0[128 * 64];
    __shared__ __align__(16) int8_t Bs0[128 * 64];
    __shared__ __align__(16) int8_t As1[128 * 64];
    __shared__ __align__(16) int8_t Bs1[128 * 64];

    const int tid  = threadIdx.x;
    const int lane = tid & 63;
    const int wave = tid >> 6;
    const int wr   = wave >> 1;
    const int wc   = wave & 1;

    // ---- bijective XCD-chunked block swizzle (m204 form) ----
    constexpr int NXB = ND / 128;
    const int nwg = gridDim.x;
    const int q   = nwg >> 3, r = nwg & 7;
    const int xcd = blockIdx.x & 7, loc = blockIdx.x >> 3;
    const int nb  = (xcd < r ? xcd * (q + 1) : r * (q + 1) + (xcd - r) * q) + loc;
    const int bm  = (nb / NXB) * 128;
    const int bn  = (nb % NXB) * 128;

    i32x4 acc[4][4] = {};

    // ---- staging: thread t -> rows t>>2 and (t>>2)+64, LDS slot t&3 (linear
    //      dest); global chunk pre-swizzled: (t&3) ^ ((row>>1)&3), row>>1==t>>3
    const int srow = tid >> 2;                                // 0..63
    const int soff = (((tid & 3) ^ ((tid >> 3) & 3)) << 4);
    const int8_t* gA = A + (size_t)(bm + srow) * KD + soff;
    const int8_t* gB = B + (size_t)(bn + srow) * KD + soff;
    const int ldst = tid * 16;

#define STAGE(LA, LB, ktb)                                                     \
    do {                                                                       \
        const int8_t* a_ = gA + (ktb);                                         \
        const int8_t* b_ = gB + (ktb);                                         \
        load16_to_lds(a_,                   LA + ldst);                        \
        load16_to_lds(a_ + (size_t)64 * KD, LA + 4096 + ldst);                 \
        load16_to_lds(b_,                   LB + ldst);                        \
        load16_to_lds(b_ + (size_t)64 * KD, LB + 4096 + ldst);                 \
    } while (0)

    // ---- fragment read addressing (swizzled, 2-way residual = free) ----
    const int fr = lane & 15;
    const int q4 = lane >> 4;
    const int cs = ((q4 ^ ((fr >> 1) & 3)) << 4);
    int aoff[4], boff[4];
#pragma unroll
    for (int m = 0; m < 4; ++m) aoff[m] = (wr * 64 + m * 16 + fr) * 64 + cs;
#pragma unroll
    for (int n = 0; n < 4; ++n) boff[n] = (wc * 64 + n * 16 + fr) * 64 + cs;

#define COMPUTE(LA, LB)                                                        \
    do {                                                                       \
        i32x4 af[4], bf[4];                                                    \
        _Pragma("unroll")                                                      \
        for (int m = 0; m < 4; ++m)                                            \
            af[m] = *reinterpret_cast<const i32x4*>(LA + aoff[m]);             \
        _Pragma("unroll")                                                      \
        for (int n = 0; n < 4; ++n)                                            \
            bf[n] = *reinterpret_cast<const i32x4*>(LB + boff[n]);             \
        __builtin_amdgcn_s_setprio(1);                                         \
        _Pragma("unroll")                                                      \
        for (int m = 0; m < 4; ++m)                                            \
            _Pragma("unroll")                                                  \
            for (int n = 0; n < 4; ++n)                                        \
                acc[m][n] = __builtin_amdgcn_mfma_i32_16x16x64_i8(             \
                    af[m], bf[n], acc[m][n], 0, 0, 0);                         \
        __builtin_amdgcn_s_setprio(0);                                         \
    } while (0)

    constexpr int NT = KD / 64;     // 12 (GEMM1) or 48 (GEMM2): even, >= 4
    STAGE(As0, Bs0, 0);             // tiles 0,1 in flight: 8 loads outstanding
    STAGE(As1, Bs1, 64);

    for (int t = 0; t < NT - 2; t += 2) {
        VMCNT4(); BAR();                      // own tile-t loads landed + all
        COMPUTE(As0, Bs0);                    // waves agree: tile t resident
        BAR();                                // all waves done reading buf0
        STAGE(As0, Bs0, (t + 2) * 64);        // restage: back to 8 in flight
        VMCNT4(); BAR();                      // tile t+1 resident
        COMPUTE(As1, Bs1);
        BAR();
        STAGE(As1, Bs1, (t + 3) * 64);
    }
    // tail: tiles NT-2, NT-1 in flight (8 loads)
    VMCNT4(); BAR();
    COMPUTE(As0, Bs0);
    VMCNT0(); BAR();                          // last tile fully landed, all waves
    COMPUTE(As1, Bs1);
#undef STAGE
#undef COMPUTE

    // ---- epilogue ----
    const float sAW = kA[0] * kW[0] * (1.0f / 16129.0f);   // (kA/127)*(kW/127)
    float kq = 1.0f;
    if constexpr (EPI1) kq = kQ[0];

    const int row0 = bm + wr * 64 + (q4 << 2);
    const int col0 = bn + wc * 64 + fr;
#pragma unroll
    for (int m = 0; m < 4; ++m) {
#pragma unroll
        for (int n = 0; n < 4; ++n) {
            const int col = col0 + n * 16;
            const float bv = bias[col];
#pragma unroll
            for (int j = 0; j < 4; ++j) {
                const int row = row0 + m * 16 + j;
                float h = (float)acc[m][n][j] * sAW + bv;
                if constexpr (EPI1) {
                    float g  = 0.5f * h * (1.0f + erff(h * 0.70710678118654752f));
                    float xc = fminf(fmaxf(g / kq, -1.0f), 1.0f);
                    qout[(size_t)row * ND + col] = (int8_t)(int)rintf(xc * 127.0f);
                } else {
                    if (row < MROWS)
                        fout[(size_t)row * ND + col] = h;
                }
            }
        }
    }
}

// ---------------------------------------------------------------------------
extern "C" void kernel_launch(void* const* d_in, const int* in_sizes, int n_in,
                              void* d_out, int out_size, void* d_ws, size_t ws_size,
                              hipStream_t stream) {
    const float* hidden = (const float*)d_in[0];
    const float* W1     = (const float*)d_in[1];
    const float* b1     = (const float*)d_in[2];
    const float* W2     = (const float*)d_in[3];
    const float* b2     = (const float*)d_in[4];
    const float* ka1    = (const float*)d_in[5];
    const float* kw1    = (const float*)d_in[6];
    const float* ka2    = (const float*)d_in[7];
    const float* kw2    = (const float*)d_in[8];
    float* out = (float*)d_out;

    int8_t* a8  = (int8_t*)d_ws;                    //  [MPAD][DDIM]
    int8_t* w1q = a8  + (size_t)MPAD * DDIM;        //  [HDIM][DDIM]
    int8_t* w2q = w1q + (size_t)HDIM * DDIM;        //  [DDIM][HDIM]
    int8_t* h8  = w2q + (size_t)DDIM * HDIM;        //  [MPAD][HDIM]

    {
        constexpr int GTOT = (MPAD * DDIM + 2 * HDIM * DDIM) / 4;
        quant_fused_kernel<<<(GTOT + 255) / 256, 256, 0, stream>>>(
            hidden, W1, W2, a8, w1q, w2q, ka1, kw1, kw2);
    }

    gemm_i8_kernel<DDIM, HDIM, true>
        <<<(HDIM / 128) * (MPAD / 128), 256, 0, stream>>>
        (a8, w1q, h8, nullptr, b1, ka1, kw1, ka2);

    gemm_i8_kernel<HDIM, DDIM, false>
        <<<(DDIM / 128) * (MPAD / 128), 256, 0, stream>>>
        (h8, w2q, nullptr, out, b2, ka2, kw2, nullptr);
}